// Round 5
// baseline (363.510 us; speedup 1.0000x reference)
//
#include <hip/hip_runtime.h>
#include <hip/hip_bf16.h>
#include <math.h>

#define NN   50000
#define EE   800000
#define INF  512
#define HIDF 256
#define OUTF 64
#define MTILES (NN/16)   // 3125

using short8 = __attribute__((ext_vector_type(8))) short;
using short4v = __attribute__((ext_vector_type(4))) short;
using f32x4  = __attribute__((ext_vector_type(4))) float;

static __device__ __forceinline__ short f2bf(float f){
  unsigned u = __builtin_bit_cast(unsigned, f);
  u += 0x7fff + ((u >> 16) & 1);        // round-to-nearest-even
  return (short)(u >> 16);
}
static __device__ __forceinline__ float bf2f(short s){
  unsigned u = ((unsigned)(unsigned short)s) << 16;
  return __builtin_bit_cast(float, u);
}

// ---- fused prep: row_ptr (blocks 0..195) | W1 pack (196..707) | W2^T (708..771) ----
__global__ void k_prep(const int* __restrict__ a_row, int* __restrict__ row_ptr,
                       const float* __restrict__ W1, short* __restrict__ W1p,
                       const float* __restrict__ W2, short* __restrict__ W2bT){
  int b = blockIdx.x, tid = threadIdx.x;
  if (b < 196){
    int i = b * 256 + tid;
    if (i > NN) return;
    int lo = 0, hi = EE;
    while (lo < hi){ int mid = (lo + hi) >> 1; if (a_row[mid] < i) lo = mid + 1; else hi = mid; }
    row_ptr[i] = lo;
  } else if (b < 708){
    int idx = (b - 196) * 256 + tid;        // 512*256 elements
    int k = idx >> 8, col = idx & 255;
    int kk = k >> 5, k2 = k & 31;
    W1p[((kk << 8) + col) * 32 + k2] = f2bf(W1[idx]);
  } else {
    int idx = (b - 708) * 256 + tid;        // 256*64 elements
    int k = idx >> 6, n = idx & 63;
    W2bT[n * HIDF + k] = f2bf(W2[idx]);
  }
}

// ---------------- GEMM1: XW1s (8-sliced bf16) = X[NN,INF] @ W1 ----------------
// barrier-free: wave = 32 rows x 256 cols, B-frags straight from global.
// Output layout: 8 column-slices of 32 cols; slice s is contiguous [NN][32]
// (3.2 MB: fits one XCD's 4MB L2 -> spmm1 gathers become L2-resident per XCD).
__global__ __launch_bounds__(128) void k_gemm1(const float* __restrict__ X,
                                               const short* __restrict__ W1p,
                                               short* __restrict__ XW1s){
  int wave = threadIdx.x >> 6, lane = threadIdx.x & 63;
  int l16 = lane & 15, quad = lane >> 4;
  int m0 = blockIdx.x * 64 + wave * 32;
  int r0 = min(m0 + l16, NN - 1);             // clamp reads; stores are guarded
  int r1 = min(m0 + 16 + l16, NN - 1);
  const float* arow0 = X + (size_t)r0 * INF + quad * 8;
  const float* arow1 = X + (size_t)r1 * INF + quad * 8;

  f32x4 acc0[16], acc1[16];
  #pragma unroll
  for (int t = 0; t < 16; t++){ acc0[t] = (f32x4){0.f,0.f,0.f,0.f}; acc1[t] = (f32x4){0.f,0.f,0.f,0.f}; }

  for (int kk = 0; kk < INF/32; kk++){
    const float4* ap0 = (const float4*)(arow0 + kk * 32);
    const float4* ap1 = (const float4*)(arow1 + kk * 32);
    float4 a00 = ap0[0], a01 = ap0[1];
    float4 a10 = ap1[0], a11 = ap1[1];
    short8 af0, af1;
    af0[0]=f2bf(a00.x); af0[1]=f2bf(a00.y); af0[2]=f2bf(a00.z); af0[3]=f2bf(a00.w);
    af0[4]=f2bf(a01.x); af0[5]=f2bf(a01.y); af0[6]=f2bf(a01.z); af0[7]=f2bf(a01.w);
    af1[0]=f2bf(a10.x); af1[1]=f2bf(a10.y); af1[2]=f2bf(a10.z); af1[3]=f2bf(a10.w);
    af1[4]=f2bf(a11.x); af1[5]=f2bf(a11.y); af1[6]=f2bf(a11.z); af1[7]=f2bf(a11.w);

    const short* bchunk = W1p + kk * (256*32);
    #pragma unroll
    for (int nt = 0; nt < 16; nt++){
      short8 bf = *(const short8*)(bchunk + (nt*16 + l16) * 32 + quad * 8);
      acc0[nt] = __builtin_amdgcn_mfma_f32_16x16x32_bf16(af0, bf, acc0[nt], 0, 0, 0);
      acc1[nt] = __builtin_amdgcn_mfma_f32_16x16x32_bf16(af1, bf, acc1[nt], 0, 0, 0);
    }
  }
  #pragma unroll
  for (int nt = 0; nt < 16; nt++){
    int s = nt >> 1;                          // slice = col/32
    short* base = XW1s + (size_t)s * NN * 32 + (nt & 1) * 16 + l16;
    #pragma unroll
    for (int r = 0; r < 4; r++){
      int row0 = m0 + quad*4 + r;
      int row1 = m0 + 16 + quad*4 + r;
      if (row0 < NN) base[(size_t)row0 * 32] = f2bf(acc0[nt][r]);
      if (row1 < NN) base[(size_t)row1 * 32] = f2bf(acc1[nt][r]);
    }
  }
}

// ---- SpMM1 + ReLU + dropout, XCD-sliced: block b gathers ONLY from slice b&7
// ---- (3.2MB, resident in that XCD's L2). wave = 4 rows x 4 edge-grps x 4 lanes.
__global__ __launch_bounds__(256) void k_spmm1(const int* __restrict__ row_ptr,
                                               const int* __restrict__ a_col,
                                               const float* __restrict__ a_val,
                                               const short* __restrict__ XW1s,
                                               const int* __restrict__ drop_mask,
                                               short* __restrict__ hb){
  int s  = blockIdx.x & 7;                 // slice == XCD (blocks round-robin XCDs)
  int rg = blockIdx.x >> 3;                // row group: 16 rows/block
  int wave = threadIdx.x >> 6, lane = threadIdx.x & 63;
  int row_local = lane >> 4;               // 4 rows per wave
  int grp = (lane >> 2) & 3;               // 4 edge groups per row
  int q   = lane & 3;                      // 4 lanes x 16B cover the 64B slice entry
  int r = rg * 16 + wave * 4 + row_local;
  int es = row_ptr[r], ee = row_ptr[r+1];
  const short* Xs = XW1s + (size_t)s * NN * 32 + q * 8;

  float acc[8] = {0,0,0,0,0,0,0,0};
  int i = es + grp;
  for (; i + 4 < ee; i += 8){              // 2 gathers in flight per lane
    float v0 = a_val[i];     int c0 = a_col[i];
    float v1 = a_val[i+4];   int c1 = a_col[i+4];
    short8 x0 = *(const short8*)(Xs + (size_t)c0 * 32);
    short8 x1 = *(const short8*)(Xs + (size_t)c1 * 32);
    #pragma unroll
    for (int j = 0; j < 8; j++){ acc[j] += v0 * bf2f(x0[j]); acc[j] += v1 * bf2f(x1[j]); }
  }
  for (; i < ee; i += 4){
    float v = a_val[i];  int c = a_col[i];
    short8 x = *(const short8*)(Xs + (size_t)c * 32);
    #pragma unroll
    for (int j = 0; j < 8; j++) acc[j] += v * bf2f(x[j]);
  }
  #pragma unroll
  for (int j = 0; j < 8; j++){             // reduce over the 4 edge groups
    acc[j] += __shfl_xor(acc[j], 4);
    acc[j] += __shfl_xor(acc[j], 8);
  }
  if (grp == 0){                           // lanes q=0..3 of each row write 64B
    const int* dm = drop_mask + (size_t)r * HIDF + s * 32 + q * 8;
    int4 d0 = *(const int4*)(dm);
    int4 d1 = *(const int4*)(dm + 4);
    short8 o;
    o[0] = f2bf(fmaxf(acc[0],0.f) * (float)d0.x * 2.0f);
    o[1] = f2bf(fmaxf(acc[1],0.f) * (float)d0.y * 2.0f);
    o[2] = f2bf(fmaxf(acc[2],0.f) * (float)d0.z * 2.0f);
    o[3] = f2bf(fmaxf(acc[3],0.f) * (float)d0.w * 2.0f);
    o[4] = f2bf(fmaxf(acc[4],0.f) * (float)d1.x * 2.0f);
    o[5] = f2bf(fmaxf(acc[5],0.f) * (float)d1.y * 2.0f);
    o[6] = f2bf(fmaxf(acc[6],0.f) * (float)d1.z * 2.0f);
    o[7] = f2bf(fmaxf(acc[7],0.f) * (float)d1.w * 2.0f);
    *(short8*)(hb + (size_t)r * HIDF + s * 32 + q * 8) = o;
  }
}

// -------- GEMM2: HW2s (4-sliced bf16) = h[NN,HIDF] @ W2; slice = nt --------
__global__ __launch_bounds__(256) void k_gemm2(const short* __restrict__ A,  // hb
                                               const short* __restrict__ BT, // [OUTF][HIDF]
                                               short* __restrict__ HW2s){
  int wave = threadIdx.x >> 6, lane = threadIdx.x & 63;
  int tile_m = blockIdx.x * 4 + wave;
  if (tile_m >= MTILES) return;
  int m0 = tile_m * 16, l16 = lane & 15, quad = lane >> 4;

  f32x4 acc[4];
  #pragma unroll
  for (int t = 0; t < 4; t++) acc[t] = (f32x4){0.f,0.f,0.f,0.f};

  const short* ar = A + (size_t)(m0 + l16) * HIDF + quad * 8;
  for (int kk = 0; kk < HIDF/32; kk++){
    short8 af = *(const short8*)(ar + kk * 32);
    #pragma unroll
    for (int nt = 0; nt < 4; nt++){
      short8 bf = *(const short8*)(BT + (size_t)(nt*16 + l16) * HIDF + kk*32 + quad*8);
      acc[nt] = __builtin_amdgcn_mfma_f32_16x16x32_bf16(af, bf, acc[nt], 0, 0, 0);
    }
  }
  #pragma unroll
  for (int nt = 0; nt < 4; nt++){          // slice nt: contiguous [NN][16] (1.6MB)
    short* base = HW2s + (size_t)nt * NN * 16 + l16;
    #pragma unroll
    for (int r = 0; r < 4; r++)
      base[(size_t)(m0 + quad*4 + r) * 16] = f2bf(acc[nt][r]);
  }
}

// -- SpMM2 raw scores, XCD-sliced: slice = blockIdx&3 (consistent with %8 XCD
// -- mapping since 4|8; per-XCD working set 1.6MB). Writes raw fp32 to d_out.
__global__ __launch_bounds__(256) void k_spmm2(const int* __restrict__ row_ptr,
                                               const int* __restrict__ a_col,
                                               const float* __restrict__ a_val,
                                               const short* __restrict__ HW2s,
                                               float* __restrict__ out){
  int t  = blockIdx.x & 3;                 // slice of 16 classes
  int rg = blockIdx.x >> 2;                // 16 rows/block
  int wave = threadIdx.x >> 6, lane = threadIdx.x & 63;
  int row_local = lane >> 4;
  int grp = (lane >> 2) & 3;
  int q   = lane & 3;                      // 4 lanes x 8B cover the 32B slice entry
  int r = rg * 16 + wave * 4 + row_local;
  int es = row_ptr[r], ee = row_ptr[r+1];
  const short* Hs = HW2s + (size_t)t * NN * 16 + q * 4;

  float acc[4] = {0,0,0,0};
  int i = es + grp;
  for (; i + 4 < ee; i += 8){
    float v0 = a_val[i];     int c0 = a_col[i];
    float v1 = a_val[i+4];   int c1 = a_col[i+4];
    short4v x0 = *(const short4v*)(Hs + (size_t)c0 * 16);
    short4v x1 = *(const short4v*)(Hs + (size_t)c1 * 16);
    #pragma unroll
    for (int j = 0; j < 4; j++){ acc[j] += v0 * bf2f(x0[j]); acc[j] += v1 * bf2f(x1[j]); }
  }
  for (; i < ee; i += 4){
    float v = a_val[i];  int c = a_col[i];
    short4v x = *(const short4v*)(Hs + (size_t)c * 16);
    #pragma unroll
    for (int j = 0; j < 4; j++) acc[j] += v * bf2f(x[j]);
  }
  #pragma unroll
  for (int j = 0; j < 4; j++){
    acc[j] += __shfl_xor(acc[j], 4);
    acc[j] += __shfl_xor(acc[j], 8);
  }
  if (grp == 0){
    float4 o4 = { acc[0], acc[1], acc[2], acc[3] };
    *(float4*)(out + (size_t)r * OUTF + t * 16 + q * 4) = o4;
  }
}

// ---- log_softmax in-place on out: wave = 1 row (64 classes = 64 lanes) ----
__global__ __launch_bounds__(256) void k_lsm(float* __restrict__ out){
  int wave = threadIdx.x >> 6, lane = threadIdx.x & 63;
  int r = blockIdx.x * 4 + wave;
  float x = out[(size_t)r * OUTF + lane];
  float m = x;
  #pragma unroll
  for (int o = 1; o <= 32; o <<= 1) m = fmaxf(m, __shfl_xor(m, o));
  float ssum = expf(x - m);
  #pragma unroll
  for (int o = 1; o <= 32; o <<= 1) ssum += __shfl_xor(ssum, o);
  out[(size_t)r * OUTF + lane] = x - m - logf(ssum);
}

extern "C" void kernel_launch(void* const* d_in, const int* in_sizes, int n_in,
                              void* d_out, int out_size, void* d_ws, size_t ws_size,
                              hipStream_t stream) {
  const float* X      = (const float*)d_in[0];
  const float* W1     = (const float*)d_in[1];
  const float* W2     = (const float*)d_in[2];
  const int*   a_row  = (const int*)d_in[3];
  const int*   a_col  = (const int*)d_in[4];
  const float* a_val  = (const float*)d_in[5];
  const int*   drop   = (const int*)d_in[6];
  float*       out    = (float*)d_out;

  char* ws = (char*)d_ws;
  int*   row_ptr = (int*)  (ws);                       //   200,704 B
  short* W1p     = (short*)(ws + 200704);              //   262,144 B
  short* W2bT    = (short*)(ws + 462848);              //    32,768 B
  short* XW1s    = (short*)(ws + 495616);              // 25,600,000 B (8 slices)
  short* hb      = (short*)(ws + 26095616);            // 25,600,000 B
  short* HW2s    = (short*)(ws + 51695616);            //  6,400,000 B (4 slices)

  k_prep<<<772, 256, 0, stream>>>(a_row, row_ptr, W1, W1p, W2, W2bT);
  k_gemm1<<<(NN + 63)/64, 128, 0, stream>>>(X, W1p, XW1s);
  k_spmm1<<<8 * (NN/16), 256, 0, stream>>>(row_ptr, a_col, a_val, XW1s, drop, hb);
  k_gemm2<<<(MTILES + 3)/4, 256, 0, stream>>>(hb, W2bT, HW2s);
  k_spmm2<<<4 * (NN/16), 256, 0, stream>>>(row_ptr, a_col, a_val, HW2s, out);
  k_lsm<<<NN/4, 256, 0, stream>>>(out);
}